// Round 5
// baseline (113.117 us; speedup 1.0000x reference)
//
#include <hip/hip_runtime.h>
#include <math.h>

#define NB 1024   // batch
#define NC 64     // input dim
#define NH 128    // hidden dim
#define MAX_IT 500
#define TOLF 1e-3f

#define PSTR 65   // uint2 stride of P/Z arrays (130 dwords: 4-way max on staging writes, free reads)
#define TSTR 66   // dword stride of T arrays (2-way everywhere = free)

typedef _Float16 h2 __attribute__((ext_vector_type(2)));

#if __has_builtin(__builtin_amdgcn_fdot2)
#define FDOT2(a, b, c) __builtin_amdgcn_fdot2((a), (b), (c), false)
#else
#define FDOT2(a, b, c) fmaf((float)(a).x, (float)(b).x, fmaf((float)(a).y, (float)(b).y, (c)))
#endif

#if __has_builtin(__builtin_amdgcn_wave_barrier)
#define WAVE_FENCE() __builtin_amdgcn_wave_barrier()
#else
#define WAVE_FENCE()
#endif

__device__ __forceinline__ unsigned pack_h2(float a, float b) {
    union { h2 h; unsigned u; } cv;
    cv.h.x = (_Float16)a; cv.h.y = (_Float16)b; return cv.u;
}
__device__ __forceinline__ h2 as_h2(unsigned u) {
    union { unsigned u; h2 h; } cv; cv.u = u; return cv.h;
}
__device__ __forceinline__ float rcp_fast(float x) {
#if __has_builtin(__builtin_amdgcn_rcpf)
    return __builtin_amdgcn_rcpf(x);
#else
    return 1.0f / x;
#endif
}
// sigmoid + softplus sharing one exp
__device__ __forceinline__ void sigsp(float a, float& sig, float& sp) {
    const float e = __expf(-fabsf(a));
    const float r = rcp_fast(1.0f + e);
    sig = (a >= 0.0f) ? r : e * r;
    sp  = fmaxf(a, 0.0f) + __logf(1.0f + e);
}

// One wave = one sample (lane c owns component c). LDS-weight-BW-bound
// structure (R3 measured ~4300 cyc/CU/iter = 512 KB/iter at 128 B/cyc), so:
// pin Wz1 (fwd rows l,l+64 + adjoint cols l,l+64 = 256 dwords) in REGISTERS
// per lane — at 1 wave/SIMD the spare VGPR space is free. Remaining streams
// (Wy0/Wy1 fwd+adj) stay in LDS, conflict-free via odd strides. Staging
// writes padded (the 4.1M one-time conflict cycles found in R3/R4).
__launch_bounds__(256, 1)
__global__ void blnn_kernel(const float* __restrict__ xin,
                            const float* __restrict__ Wy0,
                            const float* __restrict__ by0,
                            const float* __restrict__ Wy1,
                            const float* __restrict__ by1,
                            const float* __restrict__ Wz1,
                            const float* __restrict__ Wy2,
                            const float* __restrict__ by2,
                            const float* __restrict__ Wz2,
                            float* __restrict__ out)
{
    __shared__ __align__(16) unsigned P0i[32 * 2 * PSTR];  // Wy0 fwd: [pk][slot]
    __shared__ __align__(16) unsigned P1i[32 * 2 * PSTR];  // Wy1 fwd
    __shared__ __align__(16) unsigned PZi[64 * 2 * PSTR];  // Wz1 fwd bounce (clipped)
    __shared__ __align__(16) unsigned TZi[64 * 2 * PSTR];  // Wz1 adj bounce
    __shared__ __align__(16) unsigned T0j[64 * TSTR];      // Wy0 adj: [c][pj]
    __shared__ __align__(16) unsigned T1j[64 * TSTR];      // Wy1 adj
    __shared__ __align__(16) _Float16 xh [4][64];
    __shared__ __align__(16) _Float16 h0h[4][128];
    __shared__ __align__(16) _Float16 v1h[4][128];
    __shared__ __align__(16) _Float16 v0h[4][128];

    const int tid = threadIdx.x;
    const int s   = tid >> 6;
    const int l   = tid & 63;
    const int sample = blockIdx.x * 4 + s;

    // ---- stage weights: fp32 global -> packed fp16 LDS ----
    const float2* Wy0f2 = (const float2*)Wy0;   // [128][32] float2
    const float2* Wy1f2 = (const float2*)Wy1;
    const float2* Wz1f2 = (const float2*)Wz1;   // [128][64] float2
    for (int idx = tid; idx < 128 * 32; idx += 256) {        // P0/P1 fwd
        const int pk = idx & 31, r = idx >> 5;
        const int slot = ((r & 63) << 1) | (r >> 6);
        const float2 a = Wy0f2[idx], b = Wy1f2[idx];
        P0i[pk * 2 * PSTR + slot] = pack_h2(a.x, a.y);
        P1i[pk * 2 * PSTR + slot] = pack_h2(b.x, b.y);
    }
    for (int idx = tid; idx < 128 * 64; idx += 256) {        // PZ fwd (clip >= 0)
        const int pk = idx & 63, r = idx >> 6;
        const int slot = ((r & 63) << 1) | (r >> 6);
        const float2 a = Wz1f2[idx];
        PZi[pk * 2 * PSTR + slot] = pack_h2(fmaxf(a.x, 0.0f), fmaxf(a.y, 0.0f));
    }
    for (int idx = tid; idx < 64 * 128; idx += 256) {        // TZ adj (clip >= 0)
        const int c = idx & 127, pj = idx >> 7;
        const int slot = ((c & 63) << 1) | (c >> 6);
        TZi[pj * 2 * PSTR + slot] = pack_h2(fmaxf(Wz1[(2 * pj) * 128 + c], 0.0f),
                                            fmaxf(Wz1[(2 * pj + 1) * 128 + c], 0.0f));
    }
    for (int idx = tid; idx < 64 * 64; idx += 256) {         // T0/T1 adj [c][pj]
        const int c = idx & 63, pj = idx >> 6;
        T0j[c * TSTR + pj] = pack_h2(Wy0[(2 * pj) * 64 + c], Wy0[(2 * pj + 1) * 64 + c]);
        T1j[c * TSTR + pj] = pack_h2(Wy1[(2 * pj) * 64 + c], Wy1[(2 * pj + 1) * 64 + c]);
    }

    // per-lane constants
    const float wy2  = Wy2[l];
    const float wz2a = fmaxf(Wz2[l], 0.0f);
    const float wz2b = fmaxf(Wz2[l + 64], 0.0f);
    const float b0a = by0[l], b0b = by0[l + 64];
    const float b1a = by1[l], b1b = by1[l + 64];
    const float b2  = by2[0];
    const float z   = xin[sample * NC + l];

    __syncthreads();   // staging done — the ONLY block-wide barrier

    // ---- pin Wz1 into registers: fwd rows (l, l+64), adj cols (l, l+64) ----
    const uint2* WZ = (const uint2*)PZi;   // uint2 idx = pj*PSTR + l
    const uint2* AZ = (const uint2*)TZi;
    uint2 wzf[64], wza[64];                // 256 VGPRs — free at 1 wave/SIMD
    #pragma unroll
    for (int pj = 0; pj < 64; ++pj) {
        wzf[pj] = WZ[pj * PSTR + l];
        wza[pj] = AZ[pj * PSTR + l];
    }

    const h2* xh2  = (const h2*)&xh [s][0];
    const h2* h0h2 = (const h2*)&h0h[s][0];
    const h2* v1h2 = (const h2*)&v1h[s][0];
    const h2* v0h2 = (const h2*)&v0h[s][0];
    const uint2* W0 = (const uint2*)P0i;   // uint2 idx = pk*PSTR + l
    const uint2* W1 = (const uint2*)P1i;
    const uint2* T0q = (const uint2*)T0j;  // uint2 idx = c*(TSTR/2) + pjp
    const uint2* T1q = (const uint2*)T1j;

    float x1 = z;            // start at z
    float lam = 1.0f, prev_n = 3.4e38f;

    for (int it = 0; it < MAX_IT; ++it) {
        xh[s][l] = (_Float16)x1;
        WAVE_FENCE();

        // ---- layer 0 forward: a = Wy0 x + by0 (rows l, l+64) ----
        float c00 = b0a, c01 = 0.f, c10 = b0b, c11 = 0.f;
        #pragma unroll
        for (int pk = 0; pk < 32; pk += 2) {
            const h2 xa = xh2[pk], xb = xh2[pk + 1];
            const uint2 wA = W0[pk * PSTR + l];
            const uint2 wB = W0[(pk + 1) * PSTR + l];
            c00 = FDOT2(as_h2(wA.x), xa, c00);
            c10 = FDOT2(as_h2(wA.y), xa, c10);
            c01 = FDOT2(as_h2(wB.x), xb, c01);
            c11 = FDOT2(as_h2(wB.y), xb, c11);
        }
        float sig0a, sp0a, sig0b, sp0b;
        sigsp(c00 + c01, sig0a, sp0a);
        sigsp(c10 + c11, sig0b, sp0b);
        h0h[s][l]      = (_Float16)sp0a;
        h0h[s][l + 64] = (_Float16)sp0b;
        WAVE_FENCE();

        // ---- layer 1 forward: a = Wz1+ h0 + Wy1 x + by1 (Wz1 from REGS) ----
        c00 = b1a; c01 = 0.f; c10 = b1b; c11 = 0.f;
        #pragma unroll
        for (int pj = 0; pj < 64; pj += 2) {
            const h2 ha = h0h2[pj], hb = h0h2[pj + 1];
            c00 = FDOT2(as_h2(wzf[pj].x),     ha, c00);
            c10 = FDOT2(as_h2(wzf[pj].y),     ha, c10);
            c01 = FDOT2(as_h2(wzf[pj + 1].x), hb, c01);
            c11 = FDOT2(as_h2(wzf[pj + 1].y), hb, c11);
        }
        #pragma unroll
        for (int pk = 0; pk < 32; pk += 2) {
            const h2 xa = xh2[pk], xb = xh2[pk + 1];
            const uint2 wA = W1[pk * PSTR + l];
            const uint2 wB = W1[(pk + 1) * PSTR + l];
            c00 = FDOT2(as_h2(wA.x), xa, c00);
            c10 = FDOT2(as_h2(wA.y), xa, c10);
            c01 = FDOT2(as_h2(wB.x), xb, c01);
            c11 = FDOT2(as_h2(wB.y), xb, c11);
        }
        float sig1a, h1a, sig1b, h1b;
        sigsp(c00 + c01, sig1a, h1a);
        sigsp(c10 + c11, sig1b, h1b);
        // scalar head: p = Wz2.h1 + Wy2.x + by2 (wave butterfly)
        float p = wz2a * h1a + wz2b * h1b + wy2 * x1;
        #pragma unroll
        for (int off = 32; off > 0; off >>= 1) p += __shfl_xor(p, off, 64);
        const float e2 = __expf(-fabsf(p + b2));
        const float r2 = rcp_fast(1.0f + e2);
        const float sig2 = ((p + b2) >= 0.0f) ? r2 : e2 * r2;
        v1h[s][l]      = (_Float16)(sig2 * sig1a * wz2a);
        v1h[s][l + 64] = (_Float16)(sig2 * sig1b * wz2b);
        WAVE_FENCE();

        // ---- adjoint: v0 = sig0 * (Wz1+^T v1)  (Wz1^T from REGS) ----
        float t00 = 0.f, t01 = 0.f, t10 = 0.f, t11 = 0.f;
        #pragma unroll
        for (int pj = 0; pj < 64; pj += 2) {
            const h2 va = v1h2[pj], vb = v1h2[pj + 1];
            t00 = FDOT2(as_h2(wza[pj].x),     va, t00);
            t10 = FDOT2(as_h2(wza[pj].y),     va, t10);
            t01 = FDOT2(as_h2(wza[pj + 1].x), vb, t01);
            t11 = FDOT2(as_h2(wza[pj + 1].y), vb, t11);
        }
        v0h[s][l]      = (_Float16)(sig0a * (t00 + t01));
        v0h[s][l + 64] = (_Float16)(sig0b * (t10 + t11));
        WAVE_FENCE();

        // ---- g = x + sig2*Wy2^T + Wy1^T v1 + Wy0^T v0 (b64 T reads) ----
        float g0 = fmaf(sig2, wy2, x1), g1 = 0.f, g2 = 0.f, g3 = 0.f;
        #pragma unroll
        for (int pjp = 0; pjp < 32; ++pjp) {
            const uint2 w1 = T1q[l * (TSTR / 2) + pjp];
            g0 = FDOT2(as_h2(w1.x), v1h2[2 * pjp],     g0);
            g1 = FDOT2(as_h2(w1.y), v1h2[2 * pjp + 1], g1);
        }
        #pragma unroll
        for (int pjp = 0; pjp < 32; ++pjp) {
            const uint2 w0 = T0q[l * (TSTR / 2) + pjp];
            g2 = FDOT2(as_h2(w0.x), v0h2[2 * pjp],     g2);
            g3 = FDOT2(as_h2(w0.y), v0h2[2 * pjp + 1], g3);
        }
        const float g = (g0 + g1) + (g2 + g3);

        // ---- adaptive Richardson update (exact R3 solver) ----
        const float resid = z - g;
        float n2 = resid * resid;
        #pragma unroll
        for (int off = 32; off > 0; off >>= 1) n2 += __shfl_xor(n2, off, 64);
        const float n = sqrtf(n2);
        if (n < TOLF) break;                       // this wave is done
        if (n > prev_n * 0.999f) lam *= 0.5f;      // adaptive Richardson
        const float step = fmaxf(lam, 1.0f / (float)(it + 2));
        x1 = fmaf(step, resid, x1);
        prev_n = n;
    }

    out[sample * NC + l] = x1 + z;   // + CONVEX * z
}

extern "C" void kernel_launch(void* const* d_in, const int* in_sizes, int n_in,
                              void* d_out, int out_size, void* d_ws, size_t ws_size,
                              hipStream_t stream) {
    const float* xin = (const float*)d_in[0];
    const float* Wy0 = (const float*)d_in[1];
    const float* by0 = (const float*)d_in[2];
    const float* Wy1 = (const float*)d_in[3];
    const float* by1 = (const float*)d_in[4];
    const float* Wz1 = (const float*)d_in[5];
    const float* Wy2 = (const float*)d_in[6];
    const float* by2 = (const float*)d_in[7];
    const float* Wz2 = (const float*)d_in[8];
    float* out = (float*)d_out;

    blnn_kernel<<<dim3(NB / 4), dim3(256), 0, stream>>>(
        xin, Wy0, by0, Wy1, by1, Wz1, Wy2, by2, Wz2, out);
}